// Round 1
// 2674.003 us; speedup vs baseline: 2.6779x; 2.6779x over previous
//
#include <hip/hip_runtime.h>
#include <math.h>

#define BATCH 64
#define PIX   196
#define ENCD  2048
#define DECD  512
#define ATTD  512
#define EMBD  512
#define VOC   10000
#define LCAP  52
#define TSTEPS 51
#define XHDIM 3072   // emb(512) | gated awe(2048) | h(512)

typedef __bf16 bfv8 __attribute__((ext_vector_type(8)));
typedef float  fv4  __attribute__((ext_vector_type(4)));

__device__ __forceinline__ float bf2f(unsigned short u) {
    union { unsigned int i; float f; } x; x.i = ((unsigned int)u) << 16; return x.f;
}
__device__ __forceinline__ unsigned short f2bf(float f) {
    union { float f; unsigned int i; } x; x.f = f;
    unsigned int r = x.i + 0x7fffu + ((x.i >> 16) & 1u);
    return (unsigned short)(r >> 16);
}

// ---------------- setup: stable descending argsort + int outputs ----------------
__global__ void k_setup(const int* caps, const int* lens,
                        int* order, int* declen,
                        float* caps_out, float* declen_out, float* order_out) {
    __shared__ int sl[64];
    __shared__ int so[64];
    int tid = threadIdx.x;
    sl[tid] = lens[tid];
    __syncthreads();
    int li = sl[tid];
    int pos = 0;
    for (int j = 0; j < 64; ++j) {
        int lj = sl[j];
        if (lj > li || (lj == li && j < tid)) pos++;
    }
    so[pos] = tid;
    __syncthreads();
    int ob = so[tid];
    order[tid] = ob;
    int dl = sl[ob] - 1;
    declen[tid] = dl;
    order_out[tid] = (float)ob;
    declen_out[tid] = (float)dl;
    for (int l = 0; l < LCAP; ++l)
        caps_out[tid * LCAP + l] = (float)caps[ob * LCAP + l];
}

// ---------------- one-time: gather+convert ALL step embeddings ----------------
// emb_all[t][b][0:512] = bf16(embW[caps[order[b]][t]]); also seeds xh emb slot for t=0
__global__ void k_emb_all(const float* embW, const int* caps, const int* order,
                          unsigned short* emb_all, unsigned short* xh) {
    int b = blockIdx.x, t = blockIdx.y, tid = threadIdx.x;   // 128 threads, 4 f32 each
    int tok = caps[order[b] * LCAP + t];
    float4 v = *(const float4*)(embW + (size_t)tok * EMBD + tid * 4);
    ushort4 o;
    o.x = f2bf(v.x); o.y = f2bf(v.y); o.z = f2bf(v.z); o.w = f2bf(v.w);
    *(ushort4*)(emb_all + ((size_t)t * 64 + b) * EMBD + tid * 4) = o;
    if (t == 0)
        *(ushort4*)(xh + (size_t)b * XHDIM + tid * 4) = o;
}

// ---------------- one-time: tiled transpose + f32->bf16 convert ----------------
// dst[c][r] = bf16(src[r][c]) ; src is RxC row-major, dst is CxR row-major (stride R)
__global__ __launch_bounds__(256) void k_cvt_T(const float* src, unsigned short* dst,
                                               int R, int C) {
    __shared__ float tile[64][65];
    int c0 = blockIdx.x * 64, r0 = blockIdx.y * 64, tid = threadIdx.x;
    for (int idx = tid; idx < 4096; idx += 256) {
        int r = idx >> 6, c = idx & 63;
        float v = 0.f;
        if (r0 + r < R && c0 + c < C) v = src[(size_t)(r0 + r) * C + c0 + c];
        tile[r][c] = v;
    }
    __syncthreads();
    for (int idx = tid; idx < 4096; idx += 256) {
        int c = idx >> 6, r = idx & 63;
        if (c0 + c < C && r0 + r < R)
            dst[(size_t)(c0 + c) * R + r0 + r] = f2bf(tile[r][c]);
    }
}

// Wcomb[j][k] = k<2560 ? Wih[j][k] : Whh[j][k-2560]   (bf16, row-major 2048x3072)
__global__ void k_cvt_comb(const float* Wih, const float* Whh, unsigned short* W) {
    int j = blockIdx.x, tid = threadIdx.x;
    for (int k = tid * 4; k < XHDIM; k += 1024) {
        const float* src = (k < 2560) ? (Wih + (size_t)j * 2560 + k)
                                      : (Whh + (size_t)j * 512 + (k - 2560));
        float4 v = *(const float4*)src;
        ushort4 o;
        o.x = f2bf(v.x); o.y = f2bf(v.y); o.z = f2bf(v.z); o.w = f2bf(v.w);
        *(ushort4*)(W + (size_t)j * XHDIM + k) = o;
    }
}

// enc_bf[b][p][c] = bf16(enc[order[b]][p][c])  (sorted order baked in)
__global__ void k_cvt_enc(const float* enc, const int* order, unsigned short* enc_bf) {
    int b = blockIdx.x, p = blockIdx.y, tid = threadIdx.x;
    const float* src = enc + ((size_t)order[b] * PIX + p) * ENCD + tid * 8;
    float4 v0 = *(const float4*)src;
    float4 v1 = *(const float4*)(src + 4);
    unsigned short o[8];
    o[0] = f2bf(v0.x); o[1] = f2bf(v0.y); o[2] = f2bf(v0.z); o[3] = f2bf(v0.w);
    o[4] = f2bf(v1.x); o[5] = f2bf(v1.y); o[6] = f2bf(v1.z); o[7] = f2bf(v1.w);
    *(uint4*)(enc_bf + ((size_t)b * PIX + p) * ENCD + tid * 8) = *(uint4*)o;
}

// ---------------- mean over pixels (sorted order) ----------------
__global__ void k_mean(const float* enc, const int* order, float* meanv) {
    int b = blockIdx.x;
    int col = blockIdx.y * 256 + threadIdx.x;
    int ob = order[b];
    const float* base = enc + (size_t)ob * PIX * ENCD + col;
    float acc = 0.f;
    for (int p = 0; p < PIX; ++p) acc += base[(size_t)p * ENCD];
    meanv[b * ENCD + col] = acc * (1.0f / (float)PIX);
}

// ---------------- h0/c0 tiled GEMM; h path also seeds xh h-slot ----------------
__global__ __launch_bounds__(256) void k_h0c0(const float* meanv,
                                              const float* WH, const float* bH,
                                              const float* WC, const float* bC,
                                              float* h, float* c, unsigned short* xh) {
    __shared__ float As[64 * 33];
    __shared__ float Bs[32 * 65];
    int nt = blockIdx.x, tid = threadIdx.x;
    const float* W; const float* bias; float* out; int j0; bool isH;
    if (nt < 8) { W = WH; bias = bH; out = h; j0 = nt * 64; isH = true; }
    else        { W = WC; bias = bC; out = c; j0 = (nt - 8) * 64; isH = false; }
    float acc[4][4] = {};
    int tr = tid & 15, tc = tid >> 4;
    for (int k0 = 0; k0 < ENCD; k0 += 32) {
        for (int idx = tid; idx < 512; idx += 256) {
            int rl = idx >> 3, k4 = (idx & 7) << 2;
            float4 v = *(const float4*)(meanv + (size_t)rl * ENCD + k0 + k4);
            float* d = As + rl * 33 + k4;
            d[0] = v.x; d[1] = v.y; d[2] = v.z; d[3] = v.w;
        }
        for (int idx = tid; idx < 512; idx += 256) {
            int k = idx >> 4, j4 = (idx & 15) << 2;
            float4 v = *(const float4*)(W + (size_t)(k0 + k) * DECD + j0 + j4);
            float* d = Bs + k * 65 + j4;
            d[0] = v.x; d[1] = v.y; d[2] = v.z; d[3] = v.w;
        }
        __syncthreads();
        for (int kk = 0; kk < 32; ++kk) {
            float a[4], bb[4];
            for (int i = 0; i < 4; ++i) a[i] = As[(tr * 4 + i) * 33 + kk];
            for (int i = 0; i < 4; ++i) bb[i] = Bs[kk * 65 + tc * 4 + i];
            for (int i = 0; i < 4; ++i)
                for (int j2 = 0; j2 < 4; ++j2) acc[i][j2] += a[i] * bb[j2];
        }
        __syncthreads();
    }
    for (int i = 0; i < 4; ++i)
        for (int j2 = 0; j2 < 4; ++j2) {
            int r = tr * 4 + i, j = j0 + tc * 4 + j2;
            float v = acc[i][j2] + bias[j];
            out[r * DECD + j] = v;
            if (isH) xh[(size_t)r * XHDIM + 2560 + j] = f2bf(v);
        }
}

// =====================================================================
// Shared MFMA 64x64-tile core.  C[64][64] = A[64][K] @ Bt[64][K]^T
// 4 waves, each 32x32 (2x2 frags of 16x16x32 bf16).
// A/B frag layout (verified m89/m92 recipe): lane l holds 8 contiguous
// k-elems at row (l&15), k0 + (l>>4)*8.  D: row=(l>>4)*4+r, col=l&15.
// LDS rows padded to 40 bf16 (80B) -> 2-way max bank aliasing (free).
// nvalid: number of valid Bt rows (<=64); rest read as zero (fc tail).
// =====================================================================
__device__ __forceinline__ void mm64_core(
    const unsigned short* __restrict__ A, int lda,
    const unsigned short* __restrict__ Bt, int ldb,
    int K, int nvalid,
    unsigned short* __restrict__ As, unsigned short* __restrict__ Bs,
    fv4* __restrict__ acc)   // acc[4] = [m*2+n]
{
    const int tid = threadIdx.x;
    const int lane = tid & 63;
    const int w = tid >> 6, wr = w >> 1, wc = w & 1;
    const int lr = lane & 15, lk = (lane >> 4) << 3;
    const int sr = tid >> 2, sc = (tid & 3) << 3;
    const unsigned short* ap = A + (size_t)sr * lda + sc;
    const unsigned short* bp = Bt + (size_t)sr * ldb + sc;
    const bool bok = sr < nvalid;
    unsigned short* aw = As + sr * 40 + sc;
    unsigned short* bw = Bs + sr * 40 + sc;
    const unsigned short* a0p = As + (wr * 32 + lr) * 40 + lk;
    const unsigned short* a1p = a0p + 16 * 40;
    const unsigned short* b0p = Bs + (wc * 32 + lr) * 40 + lk;
    const unsigned short* b1p = b0p + 16 * 40;

    uint4 av = *(const uint4*)ap;
    uint4 bv;
    if (bok) bv = *(const uint4*)bp; else { bv.x = bv.y = bv.z = bv.w = 0u; }

    for (int k0 = 0; k0 < K; k0 += 32) {
        __syncthreads();                       // prior frag reads done
        *(uint4*)aw = av;
        *(uint4*)bw = bv;
        if (k0 + 32 < K) {                     // prefetch next K-slice
            av = *(const uint4*)(ap + k0 + 32);
            if (bok) bv = *(const uint4*)(bp + k0 + 32);
            else { bv.x = bv.y = bv.z = bv.w = 0u; }
        }
        __syncthreads();                       // staging visible
        bfv8 a0 = *(const bfv8*)a0p;
        bfv8 a1 = *(const bfv8*)a1p;
        bfv8 b0 = *(const bfv8*)b0p;
        bfv8 b1 = *(const bfv8*)b1p;
        acc[0] = __builtin_amdgcn_mfma_f32_16x16x32_bf16(a0, b0, acc[0], 0, 0, 0);
        acc[1] = __builtin_amdgcn_mfma_f32_16x16x32_bf16(a0, b1, acc[1], 0, 0, 0);
        acc[2] = __builtin_amdgcn_mfma_f32_16x16x32_bf16(a1, b0, acc[2], 0, 0, 0);
        acc[3] = __builtin_amdgcn_mfma_f32_16x16x32_bf16(a1, b1, acc[3], 0, 0, 0);
    }
}

#define MM64_DECL_EPI \
    int lane = threadIdx.x & 63; int w = threadIdx.x >> 6; \
    int wr = w >> 1, wc = w & 1; \
    int rg = (lane >> 4) << 2, cg = lane & 15;

// ---------------- att1 = enc_bf @ WaeT^T + b -> bf16  (M=12544,N=512,K=2048) ----
__global__ __launch_bounds__(256) void k_att1_mfma(
    const unsigned short* __restrict__ enc_bf, const unsigned short* __restrict__ WaeT,
    const float* __restrict__ bias, unsigned short* __restrict__ att1bf) {
    __shared__ __align__(16) unsigned short As[64 * 40];
    __shared__ __align__(16) unsigned short Bs[64 * 40];
    int r0 = blockIdx.x * 64, a0 = blockIdx.y * 64;
    fv4 acc[4];
    acc[0] = (fv4)0.f; acc[1] = (fv4)0.f; acc[2] = (fv4)0.f; acc[3] = (fv4)0.f;
    mm64_core(enc_bf + (size_t)r0 * ENCD, ENCD,
              WaeT + (size_t)a0 * ENCD, ENCD, ENCD, 64, As, Bs, acc);
    MM64_DECL_EPI
    #pragma unroll
    for (int m = 0; m < 2; ++m)
      #pragma unroll
      for (int n = 0; n < 2; ++n)
        #pragma unroll
        for (int r = 0; r < 4; ++r) {
            int row = r0 + wr * 32 + m * 16 + rg + r;
            int col = a0 + wc * 32 + n * 16 + cg;
            att1bf[(size_t)row * ATTD + col] = f2bf(acc[m * 2 + n][r] + bias[col]);
        }
}

// ---------------- per step: [att2 | gate] = h_bf @ W2T^T  (M=64,N=2560,K=512) ---
__global__ __launch_bounds__(256) void k_att2gate_mfma(
    const unsigned short* __restrict__ xh, const unsigned short* __restrict__ W2T,
    const float* __restrict__ bad, const float* __restrict__ bfb,
    float* __restrict__ att2, float* __restrict__ gate) {
    __shared__ __align__(16) unsigned short As[64 * 40];
    __shared__ __align__(16) unsigned short Bs[64 * 40];
    int j0 = blockIdx.x * 64;
    fv4 acc[4];
    acc[0] = (fv4)0.f; acc[1] = (fv4)0.f; acc[2] = (fv4)0.f; acc[3] = (fv4)0.f;
    mm64_core(xh + 2560, XHDIM, W2T + (size_t)j0 * DECD, DECD, DECD, 64, As, Bs, acc);
    MM64_DECL_EPI
    #pragma unroll
    for (int m = 0; m < 2; ++m)
      #pragma unroll
      for (int n = 0; n < 2; ++n)
        #pragma unroll
        for (int r = 0; r < 4; ++r) {
            int row = wr * 32 + m * 16 + rg + r;
            int jg = j0 + wc * 32 + n * 16 + cg;
            float v = acc[m * 2 + n][r];
            if (jg < ATTD) {
                att2[row * ATTD + jg] = v + bad[jg];
            } else {
                int jj = jg - ATTD;
                gate[row * ENCD + jj] = 1.f / (1.f + expf(-(v + bfb[jj])));
            }
        }
}

// ---------------- per step: gates split-K partials (M=64,N=2048,K=3072/6) ------
__global__ __launch_bounds__(256) void k_gates_mfma(
    const unsigned short* __restrict__ xh, const unsigned short* __restrict__ W,
    float* __restrict__ partial) {
    __shared__ __align__(16) unsigned short As[64 * 40];
    __shared__ __align__(16) unsigned short Bs[64 * 40];
    int jt = blockIdx.x, kc = blockIdx.y;
    fv4 acc[4];
    acc[0] = (fv4)0.f; acc[1] = (fv4)0.f; acc[2] = (fv4)0.f; acc[3] = (fv4)0.f;
    mm64_core(xh + kc * 512, XHDIM,
              W + (size_t)jt * 64 * XHDIM + kc * 512, XHDIM, 512, 64, As, Bs, acc);
    float* out = partial + (size_t)kc * (64 * 2048);
    MM64_DECL_EPI
    #pragma unroll
    for (int m = 0; m < 2; ++m)
      #pragma unroll
      for (int n = 0; n < 2; ++n)
        #pragma unroll
        for (int r = 0; r < 4; ++r) {
            int row = wr * 32 + m * 16 + rg + r;
            int col = jt * 64 + wc * 32 + n * 16 + cg;
            out[row * 2048 + col] = acc[m * 2 + n][r];
        }
}

// ---------------- batched fc: preds = mask ? hall_bf @ WfcT^T + b : 0 ----------
__global__ __launch_bounds__(256) void k_fc_mfma(
    const unsigned short* __restrict__ hallbf, const unsigned short* __restrict__ WfcT,
    const float* __restrict__ bias, const int* __restrict__ declen,
    float* __restrict__ preds) {
    __shared__ __align__(16) unsigned short As[64 * 40];
    __shared__ __align__(16) unsigned short Bs[64 * 40];
    int v0 = blockIdx.x * 64, tt = blockIdx.y;
    int nv = VOC - v0; if (nv > 64) nv = 64;
    fv4 acc[4];
    acc[0] = (fv4)0.f; acc[1] = (fv4)0.f; acc[2] = (fv4)0.f; acc[3] = (fv4)0.f;
    mm64_core(hallbf + (size_t)tt * 64 * DECD, DECD,
              WfcT + (size_t)v0 * DECD, DECD, DECD, nv, As, Bs, acc);
    MM64_DECL_EPI
    #pragma unroll
    for (int m = 0; m < 2; ++m)
      #pragma unroll
      for (int n = 0; n < 2; ++n)
        #pragma unroll
        for (int r = 0; r < 4; ++r) {
            int b = wr * 32 + m * 16 + rg + r;
            int v = v0 + wc * 32 + n * 16 + cg;
            if (v < VOC) {
                bool mask = tt < declen[b];
                preds[((size_t)b * TSTEPS + tt) * VOC + v] =
                    mask ? (acc[m * 2 + n][r] + bias[v]) : 0.f;
            }
        }
}

// ---------------- e[b,p] = relu(att1+att2).wfull + bfull  (vectored bf16) ------
__global__ void k_e(const unsigned short* att1bf, const float* att2,
                    const float* wfull, const float* bfull, float* e) {
    __shared__ float a2s[512];
    __shared__ float wfs[512];
    int b = blockIdx.x, tid = threadIdx.x;
    a2s[tid] = att2[b * ATTD + tid];
    a2s[tid + 256] = att2[b * ATTD + tid + 256];
    wfs[tid] = wfull[tid];
    wfs[tid + 256] = wfull[tid + 256];
    __syncthreads();
    int p = blockIdx.y * 4 + (tid >> 6);
    int lane = tid & 63;
    uint4 v = *(const uint4*)(att1bf + ((size_t)b * PIX + p) * ATTD + lane * 8);
    const unsigned short* us = (const unsigned short*)&v;
    float acc = 0.f;
    for (int jj = 0; jj < 8; ++jj) {
        int a = lane * 8 + jj;
        float x = bf2f(us[jj]) + a2s[a];
        x = fmaxf(x, 0.f);
        acc += x * wfs[a];
    }
    for (int off = 32; off; off >>= 1) acc += __shfl_down(acc, off);
    if (lane == 0) e[b * PIX + p] = acc + bfull[0];
}

// ---------------- softmax + awe + gated x -> xh (+ alphas out) ----------------
__global__ void k_awe(const float* e, const unsigned short* enc_bf,
                      const float* gate, const int* declen,
                      unsigned short* xh, float* alphas_out, int t) {
    __shared__ float sal[256];
    __shared__ float sred[256];
    __shared__ float sacc[2048];   // 8 p-groups x 256 cols
    int b = blockIdx.x, ch = blockIdx.y, tid = threadIdx.x;
    float ev = (tid < PIX) ? e[b * PIX + tid] : -1e30f;
    sred[tid] = ev; __syncthreads();
    for (int s = 128; s; s >>= 1) { if (tid < s) sred[tid] = fmaxf(sred[tid], sred[tid + s]); __syncthreads(); }
    float m = sred[0]; __syncthreads();
    float pv = (tid < PIX) ? expf(ev - m) : 0.f;
    sred[tid] = pv; __syncthreads();
    for (int s = 128; s; s >>= 1) { if (tid < s) sred[tid] += sred[tid + s]; __syncthreads(); }
    float inv = 1.f / sred[0];
    float al = pv * inv;
    sal[tid] = al;
    if (ch == 0 && tid < PIX) {
        bool mask = t < declen[b];
        alphas_out[((size_t)b * TSTEPS + t) * PIX + tid] = mask ? al : 0.f;
    }
    __syncthreads();
    int g = tid & 31, pp = tid >> 5;
    float acc[8] = {};
    const unsigned short* base = enc_bf + (size_t)b * PIX * ENCD + ch * 256 + g * 8;
    for (int p = pp; p < PIX; p += 8) {
        uint4 v = *(const uint4*)(base + (size_t)p * ENCD);
        const unsigned short* us = (const unsigned short*)&v;
        float a = sal[p];
        for (int jj = 0; jj < 8; ++jj) acc[jj] += a * bf2f(us[jj]);
    }
    for (int jj = 0; jj < 8; ++jj) sacc[pp * 256 + g * 8 + jj] = acc[jj];
    __syncthreads();
    float s = 0.f;
    for (int q = 0; q < 8; ++q) s += sacc[q * 256 + tid];
    int col = ch * 256 + tid;
    xh[(size_t)b * XHDIM + EMBD + col] = f2bf(gate[b * ENCD + col] * s);
}

// ---------------- LSTM pointwise update (+ hall_bf, + next-step emb) ----------
__global__ void k_update(const float* partial, const float* bih, const float* bhh,
                         const int* declen, float* h, float* c,
                         unsigned short* hallbf, const unsigned short* emb_all,
                         unsigned short* xh, int t) {
    int b = blockIdx.x, d = threadIdx.x;
    float g[4];
    for (int q = 0; q < 4; ++q) {
        int j = q * 512 + d;
        float acc = bih[j] + bhh[j];
        for (int kc = 0; kc < 6; ++kc) acc += partial[(size_t)kc * 131072 + b * 2048 + j];
        g[q] = acc;
    }
    float si = 1.f / (1.f + expf(-g[0]));
    float sf = 1.f / (1.f + expf(-g[1]));
    float gg = tanhf(g[2]);
    float so = 1.f / (1.f + expf(-g[3]));
    float c_old = c[b * DECD + d], h_old = h[b * DECD + d];
    float c_new = sf * c_old + si * gg;
    float h_new = so * tanhf(c_new);
    bool mask = t < declen[b];
    float h_keep = mask ? h_new : h_old;
    h[b * DECD + d] = h_keep;
    c[b * DECD + d] = mask ? c_new : c_old;
    xh[(size_t)b * XHDIM + 2560 + d] = f2bf(h_keep);
    hallbf[((size_t)t * 64 + b) * DECD + d] = f2bf(h_new);
    if (t + 1 < TSTEPS)
        xh[(size_t)b * XHDIM + d] = emb_all[((size_t)(t + 1) * 64 + b) * EMBD + d];
}

extern "C" void kernel_launch(void* const* d_in, const int* in_sizes, int n_in,
                              void* d_out, int out_size, void* d_ws, size_t ws_size,
                              hipStream_t stream) {
    const float* enc      = (const float*)d_in[0];
    const int*   caps     = (const int*)d_in[1];
    const int*   lens     = (const int*)d_in[2];
    const float* embW     = (const float*)d_in[3];
    const float* att_enc_W = (const float*)d_in[4];
    const float* att_enc_b = (const float*)d_in[5];
    const float* att_dec_W = (const float*)d_in[6];
    const float* att_dec_b = (const float*)d_in[7];
    const float* att_full_w = (const float*)d_in[8];
    const float* att_full_b = (const float*)d_in[9];
    const float* lstm_Wih = (const float*)d_in[10];
    const float* lstm_Whh = (const float*)d_in[11];
    const float* lstm_bih = (const float*)d_in[12];
    const float* lstm_bhh = (const float*)d_in[13];
    const float* initH_W  = (const float*)d_in[14];
    const float* initH_b  = (const float*)d_in[15];
    const float* initC_W  = (const float*)d_in[16];
    const float* initC_b  = (const float*)d_in[17];
    const float* fbeta_W  = (const float*)d_in[18];
    const float* fbeta_b  = (const float*)d_in[19];
    const float* fc_W     = (const float*)d_in[20];
    const float* fc_b     = (const float*)d_in[21];

    // outputs (flat f32): preds | caps | dec_len | alphas | order
    float* o = (float*)d_out;
    float* preds_out  = o;
    float* caps_out   = o + (size_t)BATCH * TSTEPS * VOC;
    float* declen_out = caps_out + (size_t)BATCH * LCAP;
    float* order_out  = declen_out + BATCH;
    float* alphas_out = order_out + BATCH;

    // ---------------- workspace layout ----------------
    char* wsb = (char*)d_ws;
    int* i_order  = (int*)wsb;
    int* i_declen = i_order + 64;
    float* f = (float*)(wsb + 512);
    float* f_h     = f;  f += (size_t)BATCH * DECD;
    float* f_c     = f;  f += (size_t)BATCH * DECD;
    float* f_att2  = f;  f += (size_t)BATCH * ATTD;
    float* f_gate  = f;  f += (size_t)BATCH * ENCD;
    float* f_e     = f;  f += (size_t)BATCH * PIX;
    f = (float*)(((uintptr_t)f + 255) & ~(uintptr_t)255);
    float* f_part  = f;  f += (size_t)6 * BATCH * 2048;
    // aliases inside f_part (both have pre-loop-only lifetimes/disjoint ranges):
    float* f_mean = f_part;                                   // 131072 floats
    unsigned short* WaeT = (unsigned short*)(f_part + (size_t)BATCH * ENCD); // 1M ushort
    f = (float*)(((uintptr_t)f + 255) & ~(uintptr_t)255);
    unsigned short* bf = (unsigned short*)f;
    unsigned short* xh_bf    = bf;  bf += (size_t)BATCH * XHDIM;
    unsigned short* att1_bf  = bf;  bf += (size_t)BATCH * PIX * ATTD;
    unsigned short* Wcomb_bf = bf;  bf += (size_t)2048 * XHDIM;
    unsigned short* W2T      = bf;  bf += (size_t)(ATTD + ENCD) * DECD;  // 2560x512
    unsigned short* WfcT     = bf;  bf += (size_t)VOC * DECD;            // 10000x512
    unsigned short* emb_all  = bf;  bf += (size_t)TSTEPS * BATCH * EMBD;
    unsigned short* hall_bf  = bf;  bf += (size_t)TSTEPS * BATCH * DECD;
    bf = (unsigned short*)(((uintptr_t)bf + 255) & ~(uintptr_t)255);
    unsigned short* enc_bf   = bf;  bf += (size_t)BATCH * PIX * ENCD;

    // ---------------- one-time setup ----------------
    k_setup<<<1, 64, 0, stream>>>(caps, lens, i_order, i_declen,
                                  caps_out, declen_out, order_out);
    k_emb_all<<<dim3(BATCH, TSTEPS), 128, 0, stream>>>(embW, caps, i_order,
                                                       emb_all, xh_bf);
    k_cvt_comb<<<2048, 256, 0, stream>>>(lstm_Wih, lstm_Whh, Wcomb_bf);
    k_cvt_enc<<<dim3(BATCH, PIX), 256, 0, stream>>>(enc, i_order, enc_bf);
    // transposed bf16 weights for MFMA (B^T layout: [n][k], k contiguous)
    k_cvt_T<<<dim3(8, 8),   256, 0, stream>>>(att_dec_W, W2T, DECD, ATTD);
    k_cvt_T<<<dim3(32, 8),  256, 0, stream>>>(fbeta_W, W2T + (size_t)ATTD * DECD, DECD, ENCD);
    k_cvt_T<<<dim3(8, 32),  256, 0, stream>>>(att_enc_W, WaeT, ENCD, ATTD);
    k_cvt_T<<<dim3(157, 8), 256, 0, stream>>>(fc_W, WfcT, DECD, VOC);
    k_mean<<<dim3(BATCH, ENCD / 256), 256, 0, stream>>>(enc, i_order, f_mean);
    k_h0c0<<<16, 256, 0, stream>>>(f_mean, initH_W, initH_b, initC_W, initC_b,
                                   f_h, f_c, xh_bf);
    k_att1_mfma<<<dim3(PIX, ATTD / 64), 256, 0, stream>>>(enc_bf, WaeT,
                                                          att_enc_b, att1_bf);

    // ---------------- recurrence ----------------
    for (int t = 0; t < TSTEPS; ++t) {
        k_att2gate_mfma<<<40, 256, 0, stream>>>(xh_bf, W2T, att_dec_b, fbeta_b,
                                                f_att2, f_gate);
        k_e<<<dim3(BATCH, 49), 256, 0, stream>>>(att1_bf, f_att2, att_full_w,
                                                 att_full_b, f_e);
        k_awe<<<dim3(BATCH, 8), 256, 0, stream>>>(f_e, enc_bf, f_gate, i_declen,
                                                  xh_bf, alphas_out, t);
        k_gates_mfma<<<dim3(32, 6), 256, 0, stream>>>(xh_bf, Wcomb_bf, f_part);
        k_update<<<BATCH, DECD, 0, stream>>>(f_part, lstm_bih, lstm_bhh, i_declen,
                                             f_h, f_c, hall_bf, emb_all, xh_bf, t);
    }

    k_fc_mfma<<<dim3((VOC + 63) / 64, TSTEPS), 256, 0, stream>>>(hall_bf, WfcT,
                                                                 fc_b, i_declen,
                                                                 preds_out);
}